// Round 18
// baseline (633.086 us; speedup 1.0000x reference)
//
#include <hip/hip_runtime.h>
#include <hip/hip_bf16.h>

#define NLIG 40000
#define NPRO 40000
#define NGRAPH 64
#define ELL 160000
#define ELP 240000
#define EPL 240000

#define RD_STRIPES 512
#define LOG2E 1.44269504f

typedef __hip_bfloat16 bf16;
typedef __attribute__((ext_vector_type(8))) short short8;
typedef __attribute__((ext_vector_type(4))) short short4v;
typedef __attribute__((ext_vector_type(4))) float f32x4;

__device__ __forceinline__ float bits2f(short s) {
  const unsigned u = ((unsigned)(unsigned short)s) << 16;
  return __uint_as_float(u);
}

// ---------- convA: f32 [M,K] -> bf16 hi/lo [M,Kp], zero-padded ----------
__global__ __launch_bounds__(256) void convA_kernel(
    const float* __restrict__ A, bf16* __restrict__ hi, bf16* __restrict__ lo,
    int M, int K, int Kp) {
  const int row = blockIdx.x * 8 + (threadIdx.x >> 5);
  if (row >= M) return;
  const int Kp4 = Kp >> 2;
  short* hp = (short*)hi;
  short* lq = (short*)lo;
  for (int c4 = threadIdx.x & 31; c4 < Kp4; c4 += 32) {
    const int k = c4 << 2;
    float v[4];
#pragma unroll
    for (int j = 0; j < 4; ++j) {
      const int kk = k + j;
      v[j] = (kk < K) ? A[(size_t)row * K + kk] : 0.f;
    }
    short4v hv, lv;
#pragma unroll
    for (int j = 0; j < 4; ++j) {
      bf16 h = __float2bfloat16(v[j]);
      float r = v[j] - __bfloat162float(h);
      bf16 l = __float2bfloat16(r);
      hv[j] = *reinterpret_cast<short*>(&h);
      lv[j] = *reinterpret_cast<short*>(&l);
    }
    *reinterpret_cast<short4v*>(&hp[(size_t)row * Kp + k]) = hv;
    *reinterpret_cast<short4v*>(&lq[(size_t)row * Kp + k]) = lv;
  }
}

// ---------- convBt: f32 B[K,256] -> bf16 hi/lo transposed [256,Kp] ----------
__global__ __launch_bounds__(256) void convBt_kernel(
    const float* __restrict__ B, bf16* __restrict__ thi, bf16* __restrict__ tlo,
    int K, int Kp) {
  const int tot = 256 * Kp;
  for (int i = blockIdx.x * 256 + threadIdx.x; i < tot; i += gridDim.x * 256) {
    const int n = i / Kp, k = i % Kp;
    float v = (k < K) ? B[(size_t)k * 256 + n] : 0.f;
    bf16 h = __float2bfloat16(v);
    float r = v - __bfloat162float(h);
    thi[i] = h;
    tlo[i] = __float2bfloat16(r);
  }
}

// ---------- MFMA GEMM, N = ncb*128 (ncb = 2 or 4), split bf16, dual-C outputs.
#define LP 40
__global__ __launch_bounds__(256) void mfma_gemm(
    const bf16* __restrict__ AhiP, const bf16* __restrict__ AloP,
    const bf16* __restrict__ BthiP, const bf16* __restrict__ BtloP,
    bf16* __restrict__ C0, bf16* __restrict__ C1, int M, int Kp, int log2ncb,
    const float* __restrict__ al0, float* __restrict__ el0,
    const float* __restrict__ ar0, float* __restrict__ er0,
    const float* __restrict__ al1, float* __restrict__ el1) {
  __shared__ short sA[2][128 * LP];
  __shared__ short sB[2][128 * LP];
  const short* Ahi = (const short*)AhiP;
  const short* Alo = (const short*)AloP;
  const short* Bthi = (const short*)BthiP;
  const short* Btlo = (const short*)BtloP;
  const int bid = blockIdx.x;
  const int ncb = 1 << log2ncb;
  const int rt = (bid >> (3 + log2ncb)) * 8 + (bid & 7);
  const int m0 = rt * 128;
  if (m0 >= M) return;
  const int n0 = ((bid >> 3) & (ncb - 1)) * 128;
  const int t = threadIdx.x;
  const int w = t >> 6, l = t & 63;
  const f32x4 zf = {0.f, 0.f, 0.f, 0.f};
  const short8 zs = {0, 0, 0, 0, 0, 0, 0, 0};
  f32x4 acc[2][8];
#pragma unroll
  for (int i = 0; i < 2; ++i)
#pragma unroll
    for (int j = 0; j < 8; ++j) acc[i][j] = zf;

  const int fr = l & 15, kg = l >> 4;

  for (int k0 = 0; k0 < Kp; k0 += 32) {
#pragma unroll
    for (int rep = 0; rep < 2; ++rep) {
      const int p = t + rep * 256;
      const int row = p >> 2, c = p & 3;
      const int gr = m0 + row;
      short8 vh = zs, vl = zs;
      if (gr < M) {
        const size_t g = (size_t)gr * Kp + k0 + c * 8;
        vh = *(const short8*)(Ahi + g);
        vl = *(const short8*)(Alo + g);
      }
      *(short8*)(&sA[0][row * LP + c * 8]) = vh;
      *(short8*)(&sA[1][row * LP + c * 8]) = vl;
    }
#pragma unroll
    for (int rep = 0; rep < 2; ++rep) {
      const int p = t + rep * 256;
      const int row = p >> 2, c = p & 3;
      const size_t g = (size_t)(n0 + row) * Kp + k0 + c * 8;
      *(short8*)(&sB[0][row * LP + c * 8]) = *(const short8*)(Bthi + g);
      *(short8*)(&sB[1][row * LP + c * 8]) = *(const short8*)(Btlo + g);
    }
    __syncthreads();
    short8 aF[2][2];
#pragma unroll
    for (int i = 0; i < 2; ++i) {
      const int r = (w * 32 + i * 16 + fr) * LP + kg * 8;
      aF[0][i] = *(const short8*)(&sA[0][r]);
      aF[1][i] = *(const short8*)(&sA[1][r]);
    }
#pragma unroll
    for (int j = 0; j < 8; ++j) {
      const int r = (j * 16 + fr) * LP + kg * 8;
      const short8 b0 = *(const short8*)(&sB[0][r]);
      const short8 b1 = *(const short8*)(&sB[1][r]);
#pragma unroll
      for (int i = 0; i < 2; ++i) {
        acc[i][j] = __builtin_amdgcn_mfma_f32_16x16x32_bf16(aF[0][i], b0, acc[i][j], 0, 0, 0);
        acc[i][j] = __builtin_amdgcn_mfma_f32_16x16x32_bf16(aF[0][i], b1, acc[i][j], 0, 0, 0);
        acc[i][j] = __builtin_amdgcn_mfma_f32_16x16x32_bf16(aF[1][i], b0, acc[i][j], 0, 0, 0);
      }
    }
    __syncthreads();
  }

  // select output half
  bf16* C = (n0 < 256) ? C0 : C1;
  const int nloc = n0 & 255;
  const float* alp = (n0 < 256) ? al0 : al1;
  const float* arp = (n0 < 256) ? ar0 : nullptr;
  float* elp = (n0 < 256) ? el0 : el1;
  float* erp = (n0 < 256) ? er0 : nullptr;

#pragma unroll
  for (int i = 0; i < 2; ++i) {
    const int rbase = m0 + w * 32 + i * 16 + kg * 4;
#pragma unroll
    for (int j = 0; j < 8; ++j) {
      const int col = nloc + j * 16 + fr;
#pragma unroll
      for (int r = 0; r < 4; ++r) {
        const int row = rbase + r;
        if (row < M) C[(size_t)row * 256 + col] = __float2bfloat16(acc[i][j][r]);
      }
    }
  }

  if (elp) {
    float alv[8], arv[8];
#pragma unroll
    for (int j = 0; j < 8; ++j) {
      alv[j] = alp[nloc + j * 16 + fr] * LOG2E;
      arv[j] = (arp && erp) ? arp[nloc + j * 16 + fr] * LOG2E : 0.f;
    }
    const int hb = nloc >> 6;
#pragma unroll
    for (int i = 0; i < 2; ++i) {
#pragma unroll
      for (int r = 0; r < 4; ++r) {
        float sl0 = 0.f, sl1 = 0.f, sr0 = 0.f, sr1 = 0.f;
#pragma unroll
        for (int j = 0; j < 4; ++j) {
          sl0 = fmaf(acc[i][j][r], alv[j], sl0);
          sr0 = fmaf(acc[i][j][r], arv[j], sr0);
          sl1 = fmaf(acc[i][j + 4][r], alv[j + 4], sl1);
          sr1 = fmaf(acc[i][j + 4][r], arv[j + 4], sr1);
        }
        sl0 += __shfl_xor(sl0, 1); sl0 += __shfl_xor(sl0, 2);
        sl0 += __shfl_xor(sl0, 4); sl0 += __shfl_xor(sl0, 8);
        sl1 += __shfl_xor(sl1, 1); sl1 += __shfl_xor(sl1, 2);
        sl1 += __shfl_xor(sl1, 4); sl1 += __shfl_xor(sl1, 8);
        sr0 += __shfl_xor(sr0, 1); sr0 += __shfl_xor(sr0, 2);
        sr0 += __shfl_xor(sr0, 4); sr0 += __shfl_xor(sr0, 8);
        sr1 += __shfl_xor(sr1, 1); sr1 += __shfl_xor(sr1, 2);
        sr1 += __shfl_xor(sr1, 4); sr1 += __shfl_xor(sr1, 8);
        const int row = m0 + w * 32 + i * 16 + kg * 4 + r;
        if (fr == 0 && row < M) {
          elp[row * 4 + hb] = sl0;
          elp[row * 4 + hb + 1] = sl1;
          if (erp) {
            erp[row * 4 + hb] = sr0;
            erp[row * 4 + hb + 1] = sr1;
          }
        }
      }
    }
  }
}

// ------------- make_wr: wr[k,h] = LOG2E * sum_d Wd[k,h*64+d]*ar[h*64+d] -------------
__global__ void make_wr_kernel(const float* __restrict__ Wd,
                               const float* __restrict__ ar,
                               float* __restrict__ wr, int K) {
  const int t = blockIdx.x * blockDim.x + threadIdx.x;
  if (t < K * 4) {
    const int k = t >> 2, h = t & 3;
    float s = 0.f;
    for (int d = 0; d < 64; ++d)
      s = fmaf(Wd[(size_t)k * 256 + h * 64 + d], ar[h * 64 + d], s);
    wr[t] = s * LOG2E;
  }
}

// ------------- er gemv (layer-1 only) -------------
__global__ __launch_bounds__(256) void er_gemv_kernel(
    const float* __restrict__ X, const float* __restrict__ wr,
    float* __restrict__ er, int n, int K) {
  __shared__ float swr[1024];
  const int t = threadIdx.x;
  for (int i = t; i < K * 4; i += blockDim.x) swr[i] = wr[i];
  __syncthreads();
  const int lane = t & 63;
  const int gw = (blockIdx.x * blockDim.x + t) >> 6;
  if (gw >= n) return;
  float a0 = 0.f, a1 = 0.f, a2 = 0.f, a3 = 0.f;
  for (int k = lane; k < K; k += 64) {
    const float x = X[(size_t)gw * K + k];
    a0 = fmaf(x, swr[k * 4 + 0], a0);
    a1 = fmaf(x, swr[k * 4 + 1], a1);
    a2 = fmaf(x, swr[k * 4 + 2], a2);
    a3 = fmaf(x, swr[k * 4 + 3], a3);
  }
#pragma unroll
  for (int o = 32; o; o >>= 1) {
    a0 += __shfl_xor(a0, o);
    a1 += __shfl_xor(a1, o);
    a2 += __shfl_xor(a2, o);
    a3 += __shfl_xor(a3, o);
  }
  if (lane == 0) {
    er[gw * 4 + 0] = a0; er[gw * 4 + 1] = a1;
    er[gw * 4 + 2] = a2; er[gw * 4 + 3] = a3;
  }
}

// ------------- CSR build -------------
__global__ void count_kernel(const int* __restrict__ dst, int* __restrict__ cnt, int E) {
  for (int i = blockIdx.x * blockDim.x + threadIdx.x; i < E; i += gridDim.x * blockDim.x)
    atomicAdd(&cnt[dst[i]], 1);
}

__global__ __launch_bounds__(256) void scan_reduce_kernel(
    const int* __restrict__ data, int* __restrict__ bsum, int n) {
  const int base = blockIdx.x * 1024;
  int s = 0;
  for (int i = threadIdx.x; i < 1024; i += 256) {
    const int idx = base + i;
    s += (idx < n) ? data[idx] : 0;
  }
#pragma unroll
  for (int o = 32; o; o >>= 1) s += __shfl_xor(s, o);
  __shared__ int ws[4];
  if ((threadIdx.x & 63) == 0) ws[threadIdx.x >> 6] = s;
  __syncthreads();
  if (threadIdx.x == 0) bsum[blockIdx.x] = ws[0] + ws[1] + ws[2] + ws[3];
}

__global__ __launch_bounds__(1024) void scan_blocksums_kernel(
    int* __restrict__ bsum, int nb) {
  __shared__ int sm[1024];
  const int t = threadIdx.x;
  const int v = (t < nb) ? bsum[t] : 0;
  sm[t] = v;
  __syncthreads();
  for (int ofs = 1; ofs < 1024; ofs <<= 1) {
    const int tmp = (t >= ofs) ? sm[t - ofs] : 0;
    __syncthreads();
    sm[t] += tmp;
    __syncthreads();
  }
  if (t < nb) bsum[t] = sm[t] - v;
}

__global__ __launch_bounds__(1024) void scan_final_kernel(
    int* __restrict__ data, const int* __restrict__ bsum, int n) {
  __shared__ int sm[1024];
  const int t = threadIdx.x;
  const int i = blockIdx.x * 1024 + t;
  const int v = (i < n) ? data[i] : 0;
  sm[t] = v;
  __syncthreads();
  for (int ofs = 1; ofs < 1024; ofs <<= 1) {
    const int tmp = (t >= ofs) ? sm[t - ofs] : 0;
    __syncthreads();
    sm[t] += tmp;
    __syncthreads();
  }
  const int c = bsum[blockIdx.x];
  if (i < n) data[i] = c + sm[t] - v;
  if (i == n - 1) data[n] = c + sm[t];
}

__global__ void fill_kernel(const int* __restrict__ src, const int* __restrict__ dst,
                            const int* __restrict__ off, int* __restrict__ cursor,
                            int* __restrict__ csrsrc, int E) {
  for (int i = blockIdx.x * blockDim.x + threadIdx.x; i < E; i += gridDim.x * blockDim.x) {
    const int d = dst[i];
    const int p = atomicAdd(&cursor[d], 1);
    csrsrc[off[d] + p] = src[i];
  }
}

// ------------- per-relation edge walk: 8-edge batches with wave-uniform
// masking (if(b<nb) is uniform -> skipped slots issue NO loads/VALU) -------------
__device__ __forceinline__ float4 agg_walk(
    const short* __restrict__ Fp, const float* __restrict__ el, float ern,
    const int* __restrict__ csr, int s0, int s1, int myh, int lane) {
  float4 acc = {0.f, 0.f, 0.f, 0.f};
  float ssum = 0.f;
  for (int p = s0; p < s1; p += 8) {
    const int nb = s1 - p;   // wave-uniform
    int srcs[8];
    float w8[8];
    short4v f8[8];
#pragma unroll
    for (int b = 0; b < 8; ++b)
      if (b < nb) srcs[b] = csr[p + b];
#pragma unroll
    for (int b = 0; b < 8; ++b)
      if (b < nb) {
        float e = el[srcs[b] * 4 + myh] + ern;
        e = e > 0.f ? e : 0.2f * e;
        w8[b] = exp2f(e);
      }
#pragma unroll
    for (int b = 0; b < 8; ++b)
      if (b < nb) f8[b] = *reinterpret_cast<const short4v*>(&Fp[(size_t)srcs[b] * 256 + lane * 4]);
#pragma unroll
    for (int b = 0; b < 8; ++b)
      if (b < nb) {
        ssum += w8[b];
        acc.x = fmaf(w8[b], bits2f(f8[b][0]), acc.x);
        acc.y = fmaf(w8[b], bits2f(f8[b][1]), acc.y);
        acc.z = fmaf(w8[b], bits2f(f8[b][2]), acc.z);
        acc.w = fmaf(w8[b], bits2f(f8[b][3]), acc.w);
      }
  }
  const float inv = ssum > 0.f ? 1.f / ssum : 0.f;
  float4 r = {acc.x * inv, acc.y * inv, acc.z * inv, acc.w * inv};
  return r;
}

// ------------- fused GAT aggregate -------------
__global__ __launch_bounds__(256) void gat_agg_fused(
    const bf16* __restrict__ F1, const float* __restrict__ el1,
    const float* __restrict__ er1, const int* __restrict__ off1,
    const int* __restrict__ csr1,
    const bf16* __restrict__ F2, const float* __restrict__ el2,
    const float* __restrict__ er2, const int* __restrict__ off2,
    const int* __restrict__ csr2,
    const float* __restrict__ bias1, const float* __restrict__ bias2,
    float* __restrict__ outF, bf16* __restrict__ outHi, bf16* __restrict__ outLo,
    const float* __restrict__ wr2, float* __restrict__ erOut,
    int n_dst) {
  const int lane = threadIdx.x & 63;
  const int myh = lane >> 4;
  const int gw = (blockIdx.x * blockDim.x + threadIdx.x) >> 6;
  if (gw >= n_dst) return;

  float4 res = agg_walk((const short*)F1, el1, er1[gw * 4 + myh],
                        csr1, off1[gw], off1[gw + 1], myh, lane);
  if (F2) {
    const float4 r2 = agg_walk((const short*)F2, el2, er2[gw * 4 + myh],
                               csr2, off2[gw], off2[gw + 1], myh, lane);
    res.x += r2.x; res.y += r2.y; res.z += r2.z; res.w += r2.w;
  }
  {
    float4 bb = *reinterpret_cast<const float4*>(&bias1[lane * 4]);
    if (bias2) {
      const float4 b2 = *reinterpret_cast<const float4*>(&bias2[lane * 4]);
      bb.x += b2.x; bb.y += b2.y; bb.z += b2.z; bb.w += b2.w;
    }
    res.x = fmaxf(res.x + bb.x, 0.f);
    res.y = fmaxf(res.y + bb.y, 0.f);
    res.z = fmaxf(res.z + bb.z, 0.f);
    res.w = fmaxf(res.w + bb.w, 0.f);
  }
  if (outF) {
    *reinterpret_cast<float4*>(&outF[(size_t)gw * 256 + lane * 4]) = res;
  } else {
    const float rv[4] = {res.x, res.y, res.z, res.w};
    short4v hv, lv;
#pragma unroll
    for (int j = 0; j < 4; ++j) {
      bf16 h = __float2bfloat16(rv[j]);
      float r = rv[j] - __bfloat162float(h);
      bf16 l = __float2bfloat16(r);
      hv[j] = *reinterpret_cast<const short*>(&h);
      lv[j] = *reinterpret_cast<const short*>(&l);
    }
    *reinterpret_cast<short4v*>(&((short*)outHi)[(size_t)gw * 256 + lane * 4]) = hv;
    *reinterpret_cast<short4v*>(&((short*)outLo)[(size_t)gw * 256 + lane * 4]) = lv;
  }
  if (erOut) {
    float4 wv0 = *reinterpret_cast<const float4*>(&wr2[(lane * 4 + 0) * 4]);
    float4 wv1 = *reinterpret_cast<const float4*>(&wr2[(lane * 4 + 1) * 4]);
    float4 wv2 = *reinterpret_cast<const float4*>(&wr2[(lane * 4 + 2) * 4]);
    float4 wv3 = *reinterpret_cast<const float4*>(&wr2[(lane * 4 + 3) * 4]);
    float e0 = res.x * wv0.x + res.y * wv1.x + res.z * wv2.x + res.w * wv3.x;
    float e1 = res.x * wv0.y + res.y * wv1.y + res.z * wv2.y + res.w * wv3.y;
    float e2 = res.x * wv0.z + res.y * wv1.z + res.z * wv2.z + res.w * wv3.z;
    float e3 = res.x * wv0.w + res.y * wv1.w + res.z * wv2.w + res.w * wv3.w;
#pragma unroll
    for (int o = 32; o; o >>= 1) {
      e0 += __shfl_xor(e0, o);
      e1 += __shfl_xor(e1, o);
      e2 += __shfl_xor(e2, o);
      e3 += __shfl_xor(e3, o);
    }
    if (lane == 0) {
      erOut[gw * 4 + 0] = e0; erOut[gw * 4 + 1] = e1;
      erOut[gw * 4 + 2] = e2; erOut[gw * 4 + 3] = e3;
    }
  }
}

// ---------- graph readout stage 1 (512 stripes) ----------
__global__ __launch_bounds__(256) void graph_sum_v3(
    const float* __restrict__ h, const int* __restrict__ gid,
    float* __restrict__ pbuf, int n) {
  __shared__ float sm[NGRAPH * 256];
  const int t = threadIdx.x;
  for (int i = t; i < NGRAPH * 256; i += 256) sm[i] = 0.f;
  __syncthreads();
  const int chunk = (n + RD_STRIPES - 1) / RD_STRIPES;
  const int lo = blockIdx.x * chunk;
  const int hiN = min(n, lo + chunk);
#pragma unroll 8
  for (int node = lo; node < hiN; ++node) {
    const int g = gid[node];
    const float v = h[(size_t)node * 256 + t];
    sm[g * 256 + t] += v;
  }
  __syncthreads();
  float* dst = pbuf + (size_t)blockIdx.x * (NGRAPH * 256);
  for (int i = t; i < NGRAPH * 256; i += 256) dst[i] = sm[i];
}

// ---------- graph readout stage 2 ----------
__global__ __launch_bounds__(256) void graph_reduce_kernel(
    const float* __restrict__ pbuf, float* __restrict__ gsum, int colofs) {
  const int g = blockIdx.x, t = threadIdx.x;
  float acc = 0.f;
#pragma unroll 8
  for (int s = 0; s < RD_STRIPES; ++s)
    acc += pbuf[(size_t)s * (NGRAPH * 256) + g * 256 + t];
  gsum[(size_t)g * 512 + colofs + t] = acc;
}

// ---------- graph node-count ----------
__global__ __launch_bounds__(256) void graph_count_kernel(
    const int* __restrict__ gid, int* __restrict__ gcnt, int n, int cntofs) {
  __shared__ int c[NGRAPH];
  if (threadIdx.x < NGRAPH) c[threadIdx.x] = 0;
  __syncthreads();
  for (int i = blockIdx.x * blockDim.x + threadIdx.x; i < n; i += gridDim.x * blockDim.x)
    atomicAdd(&c[gid[i]], 1);
  __syncthreads();
  if (threadIdx.x < NGRAPH && c[threadIdx.x])
    atomicAdd(&gcnt[cntofs + threadIdx.x], c[threadIdx.x]);
}

// ---------- final MLP ----------
__global__ __launch_bounds__(256) void mlp_kernel(
    const float* __restrict__ gsum, const int* __restrict__ gcnt,
    const float* __restrict__ Wm, const float* __restrict__ bm,
    float* __restrict__ out) {
  __shared__ float g[512];
  const int b = blockIdx.x, t = threadIdx.x;
  const float cl = fmaxf((float)gcnt[b], 1.f);
  const float cp = fmaxf((float)gcnt[64 + b], 1.f);
  for (int k = t; k < 512; k += 256)
    g[k] = gsum[(size_t)b * 512 + k] * (k < 256 ? 1.f / cl : 1.f / cp);
  __syncthreads();
  float acc = bm[t];
  for (int k = 0; k < 512; ++k) acc = fmaf(g[k], Wm[(size_t)k * 256 + t], acc);
  out[b * 256 + t] = fmaxf(acc, 0.f);
}

// =====================================================================
extern "C" void kernel_launch(void* const* d_in, const int* in_sizes, int n_in,
                              void* d_out, int out_size, void* d_ws, size_t ws_size,
                              hipStream_t stream) {
  const float* x_lig  = (const float*)d_in[0];
  const float* x_pro  = (const float*)d_in[1];
  const float* W1_ll  = (const float*)d_in[2];
  const float* al1_ll = (const float*)d_in[3];
  const float* ar1_ll = (const float*)d_in[4];
  const float* b1_ll  = (const float*)d_in[5];
  const float* W1_lps = (const float*)d_in[6];
  const float* W1_lpd = (const float*)d_in[7];
  const float* al1_lp = (const float*)d_in[8];
  const float* ar1_lp = (const float*)d_in[9];
  const float* b1_lp  = (const float*)d_in[10];
  const float* W1_pls = (const float*)d_in[11];
  const float* W1_pld = (const float*)d_in[12];
  const float* al1_pl = (const float*)d_in[13];
  const float* ar1_pl = (const float*)d_in[14];
  const float* b1_pl  = (const float*)d_in[15];
  const float* W2_ll  = (const float*)d_in[16];
  const float* al2_ll = (const float*)d_in[17];
  const float* ar2_ll = (const float*)d_in[18];
  const float* b2_ll  = (const float*)d_in[19];
  const float* W2_lps = (const float*)d_in[20];
  const float* W2_lpd = (const float*)d_in[21];
  const float* al2_lp = (const float*)d_in[22];
  const float* ar2_lp = (const float*)d_in[23];
  const float* b2_lp  = (const float*)d_in[24];
  const float* W2_pls = (const float*)d_in[25];
  const float* W2_pld = (const float*)d_in[26];
  const float* al2_pl = (const float*)d_in[27];
  const float* ar2_pl = (const float*)d_in[28];
  const float* b2_pl  = (const float*)d_in[29];
  const float* W_mlp  = (const float*)d_in[30];
  const float* b_mlp  = (const float*)d_in[31];
  const int* src_ll   = (const int*)d_in[32];
  const int* dst_ll   = (const int*)d_in[33];
  const int* src_lp   = (const int*)d_in[34];
  const int* dst_lp   = (const int*)d_in[35];
  const int* src_pl   = (const int*)d_in[36];
  const int* dst_pl   = (const int*)d_in[37];
  const int* gid_lig  = (const int*)d_in[38];
  const int* gid_pro  = (const int*)d_in[39];
  float* out = (float*)d_out;
  (void)in_sizes; (void)n_in; (void)out_size; (void)ws_size;

  // -------- workspace carving (~193 MB) --------
  size_t cur = 0;
  auto carve = [&](size_t bytes) -> char* {
    char* p = (char*)d_ws + cur;
    cur += (bytes + 511) & ~(size_t)511;
    return p;
  };
  const size_t NB   = (size_t)40000 * 256 * sizeof(float);
  const size_t NBH  = (size_t)40000 * 256 * sizeof(bf16);
  bf16* FbA   = (bf16*)carve(NBH);
  bf16* FbB   = (bf16*)carve(NBH);
  bf16* FbC   = (bf16*)carve(NBH);
  char* S1    = carve(NB);
  char* S2P   = carve(NB);
  float* hX   = (float*)carve(NB);
  float* elA  = (float*)carve((size_t)40000 * 4 * sizeof(float));
  float* erA  = (float*)carve((size_t)40000 * 4 * sizeof(float));
  float* elB  = (float*)carve((size_t)40000 * 4 * sizeof(float));
  float* erB  = (float*)carve((size_t)40000 * 4 * sizeof(float));
  float* elC  = (float*)carve((size_t)40000 * 4 * sizeof(float));
  float* erPL = (float*)carve((size_t)40000 * 4 * sizeof(float));
  float* erLP = (float*)carve((size_t)40000 * 4 * sizeof(float));
  float* wr1  = (float*)carve((size_t)256 * 4 * sizeof(float));
  float* wrA  = (float*)carve((size_t)256 * 4 * sizeof(float));
  float* wrB  = (float*)carve((size_t)256 * 4 * sizeof(float));
  bf16* Bthi  = (bf16*)carve((size_t)512 * 256 * sizeof(bf16));
  bf16* Btlo  = (bf16*)carve((size_t)512 * 256 * sizeof(bf16));
  float* gsum = (float*)carve((size_t)64 * 512 * sizeof(float));
  int* gcnt   = (int*)carve(128 * sizeof(int));
  int* bsum   = (int*)carve(1025 * sizeof(int));
  int* off_ll = (int*)carve((NLIG + 1) * sizeof(int));
  int* off_lp = (int*)carve((NPRO + 1) * sizeof(int));
  int* off_pl = (int*)carve((NLIG + 1) * sizeof(int));
  int* cursor = (int*)carve((NLIG + 1) * sizeof(int));
  int* csr_ll = (int*)carve((size_t)ELL * sizeof(int));
  int* csr_lp = (int*)carve((size_t)ELP * sizeof(int));
  int* csr_pl = (int*)carve((size_t)EPL * sizeof(int));

  // overlays / sub-pointers
  bf16* XLhi = (bf16*)S1;
  bf16* XLlo = XLhi + (size_t)40000 * 96;
  bf16* XPhi = (bf16*)S2P;
  bf16* XPlo = XPhi + (size_t)40000 * 128;
  bf16* S1hi = (bf16*)S1;
  bf16* S1lo = S1hi + (size_t)40000 * 256;
  bf16* S2hi = (bf16*)S2P;
  bf16* S2lo = S2hi + (size_t)40000 * 256;
  float* P2  = (float*)S2P;
  float* pbuf = (float*)FbA;   // 33.5 MB readout partials spans FbA+FbB (both dead)

  const int B256 = 256;
  auto thrGrid  = [](long long n) { return (int)((n + 255) / 256); };
  auto waveGrid = [](int n) { return (n + 3) / 4; };

  auto conv_a = [&](const float* A, bf16* hi, bf16* lo, int M, int K, int Kp) {
    convA_kernel<<<(M + 7) / 8, B256, 0, stream>>>(A, hi, lo, M, K, Kp);
  };
  auto run_mfma = [&](const bf16* ahi, const bf16* alo,
                      const float* Wa, const float* Wb, int K, int Kp, int M,
                      bf16* C0, bf16* C1,
                      const float* al0, float* el0, const float* ar0, float* er0,
                      const float* al1, float* el1) {
    convBt_kernel<<<256, B256, 0, stream>>>(Wa, Bthi, Btlo, K, Kp);
    if (Wb)
      convBt_kernel<<<256, B256, 0, stream>>>(Wb, Bthi + (size_t)256 * Kp,
                                              Btlo + (size_t)256 * Kp, K, Kp);
    const int log2ncb = Wb ? 2 : 1;
    const int nrt = (M + 127) / 128;
    const int nb = ((nrt + 7) / 8) * 8 * (1 << log2ncb);
    mfma_gemm<<<nb, B256, 0, stream>>>(ahi, alo, Bthi, Btlo, C0, C1, M, Kp, log2ncb,
                                       al0, el0, ar0, er0, al1, el1);
  };
  auto run_scan = [&](int* data, int n) {
    const int nb = (n + 1023) / 1024;
    scan_reduce_kernel<<<nb, B256, 0, stream>>>(data, bsum, n);
    scan_blocksums_kernel<<<1, 1024, 0, stream>>>(bsum, nb);
    scan_final_kernel<<<nb, 1024, 0, stream>>>(data, bsum, n);
  };

  // -------- CSR builds --------
  struct Rel { const int* src; const int* dst; int* off; int* csr; int E; int Nd; };
  Rel rels[3] = {
    {src_ll, dst_ll, off_ll, csr_ll, ELL, NLIG},
    {src_lp, dst_lp, off_lp, csr_lp, ELP, NPRO},
    {src_pl, dst_pl, off_pl, csr_pl, EPL, NLIG},
  };
  for (int r = 0; r < 3; ++r) {
    hipMemsetAsync(rels[r].off, 0, (rels[r].Nd + 1) * sizeof(int), stream);
    count_kernel<<<thrGrid(rels[r].E), B256, 0, stream>>>(rels[r].dst, rels[r].off, rels[r].E);
    run_scan(rels[r].off, rels[r].Nd);
    hipMemsetAsync(cursor, 0, (rels[r].Nd + 1) * sizeof(int), stream);
    fill_kernel<<<thrGrid(rels[r].E), B256, 0, stream>>>(
        rels[r].src, rels[r].dst, rels[r].off, cursor, rels[r].csr, rels[r].E);
  }

  // ================= LAYER 1 =================
  conv_a(x_lig, XLhi, XLlo, NLIG, 74, 96);
  conv_a(x_pro, XPhi, XPlo, NPRO, 128, 128);
  // merged: FbA = x_lig@W1_ll (+elA,erA), FbC = x_lig@W1_lps (+elC)
  run_mfma(XLhi, XLlo, W1_ll, W1_lps, 74, 96, NLIG,
           FbA, FbC, al1_ll, elA, ar1_ll, erA, al1_lp, elC);
  // pl src GEMM: FbB = x_pro @ W1_pls (+elB)
  run_mfma(XPhi, XPlo, W1_pls, nullptr, 128, 128, NPRO,
           FbB, nullptr, al1_pl, elB, nullptr, nullptr, nullptr, nullptr);
  // pl dst er: erB = x_lig @ (W1_pld . ar1_pl)  [LOG2E-scaled]
  make_wr_kernel<<<(74 * 4 + 255) / 256, B256, 0, stream>>>(W1_pld, ar1_pl, wr1, 74);
  er_gemv_kernel<<<waveGrid(NLIG), B256, 0, stream>>>(x_lig, wr1, erB, NLIG, 74);
  // layer-2 dst weights (scaled)
  make_wr_kernel<<<(256 * 4 + 255) / 256, B256, 0, stream>>>(W2_pld, ar2_pl, wrA, 256);
  make_wr_kernel<<<(256 * 4 + 255) / 256, B256, 0, stream>>>(W2_lpd, ar2_lp, wrB, 256);
  // fused dual agg -> S1 (bf16 split) + erPL
  gat_agg_fused<<<waveGrid(NLIG), B256, 0, stream>>>(
      FbA, elA, erA, off_ll, csr_ll,
      FbB, elB, erB, off_pl, csr_pl,
      b1_ll, b1_pl, nullptr, S1hi, S1lo, wrA, erPL, NLIG);
  // lp dst er: erB = x_pro @ (W1_lpd . ar1_lp)
  make_wr_kernel<<<(128 * 4 + 255) / 256, B256, 0, stream>>>(W1_lpd, ar1_lp, wr1, 128);
  er_gemv_kernel<<<waveGrid(NPRO), B256, 0, stream>>>(x_pro, wr1, erB, NPRO, 128);
  // fused single agg (lp: FbC) -> S2 (bf16 split) + erLP
  gat_agg_fused<<<waveGrid(NPRO), B256, 0, stream>>>(
      FbC, elC, erB, off_lp, csr_lp,
      nullptr, nullptr, nullptr, nullptr, nullptr,
      b1_lp, nullptr, nullptr, S2hi, S2lo, wrB, erLP, NPRO);

  // ================= LAYER 2 =================
  run_mfma(S1hi, S1lo, W2_ll, W2_lps, 256, 256, NLIG,
           FbA, FbC, al2_ll, elA, ar2_ll, erA, al2_lp, elC);
  run_mfma(S2hi, S2lo, W2_pls, nullptr, 256, 256, NPRO,
           FbB, nullptr, al2_pl, elB, nullptr, nullptr, nullptr, nullptr);
  gat_agg_fused<<<waveGrid(NLIG), B256, 0, stream>>>(
      FbA, elA, erA, off_ll, csr_ll,
      FbB, elB, erPL, off_pl, csr_pl,
      b2_ll, b2_pl, hX, nullptr, nullptr, nullptr, nullptr, NLIG);
  gat_agg_fused<<<waveGrid(NPRO), B256, 0, stream>>>(
      FbC, elC, erLP, off_lp, csr_lp,
      nullptr, nullptr, nullptr, nullptr, nullptr,
      b2_lp, nullptr, P2, nullptr, nullptr, nullptr, nullptr, NPRO);

  // ================= READOUT (FbA/FbB dead -> pbuf) + MLP =================
  hipMemsetAsync(gcnt, 0, 128 * sizeof(int), stream);
  graph_sum_v3<<<RD_STRIPES, B256, 0, stream>>>(hX, gid_lig, pbuf, NLIG);
  graph_reduce_kernel<<<NGRAPH, B256, 0, stream>>>(pbuf, gsum, 0);
  graph_count_kernel<<<64, B256, 0, stream>>>(gid_lig, gcnt, NLIG, 0);
  graph_sum_v3<<<RD_STRIPES, B256, 0, stream>>>(P2, gid_pro, pbuf, NPRO);
  graph_reduce_kernel<<<NGRAPH, B256, 0, stream>>>(pbuf, gsum, 256);
  graph_count_kernel<<<64, B256, 0, stream>>>(gid_pro, gcnt, NPRO, 64);
  mlp_kernel<<<64, B256, 0, stream>>>(gsum, gcnt, W_mlp, b_mlp, out);
}

// Round 19
// 594.444 us; speedup vs baseline: 1.0650x; 1.0650x over previous
//
#include <hip/hip_runtime.h>
#include <hip/hip_bf16.h>

#define NLIG 40000
#define NPRO 40000
#define NGRAPH 64
#define ELL 160000
#define ELP 240000
#define EPL 240000

#define RD_STRIPES 256
#define LOG2E 1.44269504f

typedef __hip_bfloat16 bf16;
typedef __attribute__((ext_vector_type(8))) short short8;
typedef __attribute__((ext_vector_type(4))) short short4v;
typedef __attribute__((ext_vector_type(4))) float f32x4;

__device__ __forceinline__ float bits2f(short s) {
  const unsigned u = ((unsigned)(unsigned short)s) << 16;
  return __uint_as_float(u);
}

// ---------- convA: f32 [M,K] -> bf16 hi/lo [M,Kp], zero-padded ----------
__global__ __launch_bounds__(256) void convA_kernel(
    const float* __restrict__ A, bf16* __restrict__ hi, bf16* __restrict__ lo,
    int M, int K, int Kp) {
  const int row = blockIdx.x * 8 + (threadIdx.x >> 5);
  if (row >= M) return;
  const int Kp4 = Kp >> 2;
  short* hp = (short*)hi;
  short* lq = (short*)lo;
  for (int c4 = threadIdx.x & 31; c4 < Kp4; c4 += 32) {
    const int k = c4 << 2;
    float v[4];
#pragma unroll
    for (int j = 0; j < 4; ++j) {
      const int kk = k + j;
      v[j] = (kk < K) ? A[(size_t)row * K + kk] : 0.f;
    }
    short4v hv, lv;
#pragma unroll
    for (int j = 0; j < 4; ++j) {
      bf16 h = __float2bfloat16(v[j]);
      float r = v[j] - __bfloat162float(h);
      bf16 l = __float2bfloat16(r);
      hv[j] = *reinterpret_cast<short*>(&h);
      lv[j] = *reinterpret_cast<short*>(&l);
    }
    *reinterpret_cast<short4v*>(&hp[(size_t)row * Kp + k]) = hv;
    *reinterpret_cast<short4v*>(&lq[(size_t)row * Kp + k]) = lv;
  }
}

// ---------- convBt: f32 B[K,256] -> bf16 hi/lo transposed [256,Kp] ----------
__global__ __launch_bounds__(256) void convBt_kernel(
    const float* __restrict__ B, bf16* __restrict__ thi, bf16* __restrict__ tlo,
    int K, int Kp) {
  const int tot = 256 * Kp;
  for (int i = blockIdx.x * 256 + threadIdx.x; i < tot; i += gridDim.x * 256) {
    const int n = i / Kp, k = i % Kp;
    float v = (k < K) ? B[(size_t)k * 256 + n] : 0.f;
    bf16 h = __float2bfloat16(v);
    float r = v - __bfloat162float(h);
    thi[i] = h;
    tlo[i] = __float2bfloat16(r);
  }
}

// ---------- MFMA GEMM, N = ncb*128 (ncb = 2 or 4), split bf16, dual-C outputs.
#define LP 40
__global__ __launch_bounds__(256) void mfma_gemm(
    const bf16* __restrict__ AhiP, const bf16* __restrict__ AloP,
    const bf16* __restrict__ BthiP, const bf16* __restrict__ BtloP,
    bf16* __restrict__ C0, bf16* __restrict__ C1, int M, int Kp, int log2ncb,
    const float* __restrict__ al0, float* __restrict__ el0,
    const float* __restrict__ ar0, float* __restrict__ er0,
    const float* __restrict__ al1, float* __restrict__ el1) {
  __shared__ short sA[2][128 * LP];
  __shared__ short sB[2][128 * LP];
  const short* Ahi = (const short*)AhiP;
  const short* Alo = (const short*)AloP;
  const short* Bthi = (const short*)BthiP;
  const short* Btlo = (const short*)BtloP;
  const int bid = blockIdx.x;
  const int ncb = 1 << log2ncb;
  const int rt = (bid >> (3 + log2ncb)) * 8 + (bid & 7);
  const int m0 = rt * 128;
  if (m0 >= M) return;
  const int n0 = ((bid >> 3) & (ncb - 1)) * 128;
  const int t = threadIdx.x;
  const int w = t >> 6, l = t & 63;
  const f32x4 zf = {0.f, 0.f, 0.f, 0.f};
  const short8 zs = {0, 0, 0, 0, 0, 0, 0, 0};
  f32x4 acc[2][8];
#pragma unroll
  for (int i = 0; i < 2; ++i)
#pragma unroll
    for (int j = 0; j < 8; ++j) acc[i][j] = zf;

  const int fr = l & 15, kg = l >> 4;

  for (int k0 = 0; k0 < Kp; k0 += 32) {
#pragma unroll
    for (int rep = 0; rep < 2; ++rep) {
      const int p = t + rep * 256;
      const int row = p >> 2, c = p & 3;
      const int gr = m0 + row;
      short8 vh = zs, vl = zs;
      if (gr < M) {
        const size_t g = (size_t)gr * Kp + k0 + c * 8;
        vh = *(const short8*)(Ahi + g);
        vl = *(const short8*)(Alo + g);
      }
      *(short8*)(&sA[0][row * LP + c * 8]) = vh;
      *(short8*)(&sA[1][row * LP + c * 8]) = vl;
    }
#pragma unroll
    for (int rep = 0; rep < 2; ++rep) {
      const int p = t + rep * 256;
      const int row = p >> 2, c = p & 3;
      const size_t g = (size_t)(n0 + row) * Kp + k0 + c * 8;
      *(short8*)(&sB[0][row * LP + c * 8]) = *(const short8*)(Bthi + g);
      *(short8*)(&sB[1][row * LP + c * 8]) = *(const short8*)(Btlo + g);
    }
    __syncthreads();
    short8 aF[2][2];
#pragma unroll
    for (int i = 0; i < 2; ++i) {
      const int r = (w * 32 + i * 16 + fr) * LP + kg * 8;
      aF[0][i] = *(const short8*)(&sA[0][r]);
      aF[1][i] = *(const short8*)(&sA[1][r]);
    }
#pragma unroll
    for (int j = 0; j < 8; ++j) {
      const int r = (j * 16 + fr) * LP + kg * 8;
      const short8 b0 = *(const short8*)(&sB[0][r]);
      const short8 b1 = *(const short8*)(&sB[1][r]);
#pragma unroll
      for (int i = 0; i < 2; ++i) {
        acc[i][j] = __builtin_amdgcn_mfma_f32_16x16x32_bf16(aF[0][i], b0, acc[i][j], 0, 0, 0);
        acc[i][j] = __builtin_amdgcn_mfma_f32_16x16x32_bf16(aF[0][i], b1, acc[i][j], 0, 0, 0);
        acc[i][j] = __builtin_amdgcn_mfma_f32_16x16x32_bf16(aF[1][i], b0, acc[i][j], 0, 0, 0);
      }
    }
    __syncthreads();
  }

  // select output half
  bf16* C = (n0 < 256) ? C0 : C1;
  const int nloc = n0 & 255;
  const float* alp = (n0 < 256) ? al0 : al1;
  const float* arp = (n0 < 256) ? ar0 : nullptr;
  float* elp = (n0 < 256) ? el0 : el1;
  float* erp = (n0 < 256) ? er0 : nullptr;

#pragma unroll
  for (int i = 0; i < 2; ++i) {
    const int rbase = m0 + w * 32 + i * 16 + kg * 4;
#pragma unroll
    for (int j = 0; j < 8; ++j) {
      const int col = nloc + j * 16 + fr;
#pragma unroll
      for (int r = 0; r < 4; ++r) {
        const int row = rbase + r;
        if (row < M) C[(size_t)row * 256 + col] = __float2bfloat16(acc[i][j][r]);
      }
    }
  }

  if (elp) {
    float alv[8], arv[8];
#pragma unroll
    for (int j = 0; j < 8; ++j) {
      alv[j] = alp[nloc + j * 16 + fr] * LOG2E;
      arv[j] = (arp && erp) ? arp[nloc + j * 16 + fr] * LOG2E : 0.f;
    }
    const int hb = nloc >> 6;
#pragma unroll
    for (int i = 0; i < 2; ++i) {
#pragma unroll
      for (int r = 0; r < 4; ++r) {
        float sl0 = 0.f, sl1 = 0.f, sr0 = 0.f, sr1 = 0.f;
#pragma unroll
        for (int j = 0; j < 4; ++j) {
          sl0 = fmaf(acc[i][j][r], alv[j], sl0);
          sr0 = fmaf(acc[i][j][r], arv[j], sr0);
          sl1 = fmaf(acc[i][j + 4][r], alv[j + 4], sl1);
          sr1 = fmaf(acc[i][j + 4][r], arv[j + 4], sr1);
        }
        sl0 += __shfl_xor(sl0, 1); sl0 += __shfl_xor(sl0, 2);
        sl0 += __shfl_xor(sl0, 4); sl0 += __shfl_xor(sl0, 8);
        sl1 += __shfl_xor(sl1, 1); sl1 += __shfl_xor(sl1, 2);
        sl1 += __shfl_xor(sl1, 4); sl1 += __shfl_xor(sl1, 8);
        sr0 += __shfl_xor(sr0, 1); sr0 += __shfl_xor(sr0, 2);
        sr0 += __shfl_xor(sr0, 4); sr0 += __shfl_xor(sr0, 8);
        sr1 += __shfl_xor(sr1, 1); sr1 += __shfl_xor(sr1, 2);
        sr1 += __shfl_xor(sr1, 4); sr1 += __shfl_xor(sr1, 8);
        const int row = m0 + w * 32 + i * 16 + kg * 4 + r;
        if (fr == 0 && row < M) {
          elp[row * 4 + hb] = sl0;
          elp[row * 4 + hb + 1] = sl1;
          if (erp) {
            erp[row * 4 + hb] = sr0;
            erp[row * 4 + hb + 1] = sr1;
          }
        }
      }
    }
  }
}

// ------------- make_wr: wr[k,h] = LOG2E * sum_d Wd[k,h*64+d]*ar[h*64+d] -------------
__global__ void make_wr_kernel(const float* __restrict__ Wd,
                               const float* __restrict__ ar,
                               float* __restrict__ wr, int K) {
  const int t = blockIdx.x * blockDim.x + threadIdx.x;
  if (t < K * 4) {
    const int k = t >> 2, h = t & 3;
    float s = 0.f;
    for (int d = 0; d < 64; ++d)
      s = fmaf(Wd[(size_t)k * 256 + h * 64 + d], ar[h * 64 + d], s);
    wr[t] = s * LOG2E;
  }
}

// ------------- er gemv (layer-1 only) -------------
__global__ __launch_bounds__(256) void er_gemv_kernel(
    const float* __restrict__ X, const float* __restrict__ wr,
    float* __restrict__ er, int n, int K) {
  __shared__ float swr[1024];
  const int t = threadIdx.x;
  for (int i = t; i < K * 4; i += blockDim.x) swr[i] = wr[i];
  __syncthreads();
  const int lane = t & 63;
  const int gw = (blockIdx.x * blockDim.x + t) >> 6;
  if (gw >= n) return;
  float a0 = 0.f, a1 = 0.f, a2 = 0.f, a3 = 0.f;
  for (int k = lane; k < K; k += 64) {
    const float x = X[(size_t)gw * K + k];
    a0 = fmaf(x, swr[k * 4 + 0], a0);
    a1 = fmaf(x, swr[k * 4 + 1], a1);
    a2 = fmaf(x, swr[k * 4 + 2], a2);
    a3 = fmaf(x, swr[k * 4 + 3], a3);
  }
#pragma unroll
  for (int o = 32; o; o >>= 1) {
    a0 += __shfl_xor(a0, o);
    a1 += __shfl_xor(a1, o);
    a2 += __shfl_xor(a2, o);
    a3 += __shfl_xor(a3, o);
  }
  if (lane == 0) {
    er[gw * 4 + 0] = a0; er[gw * 4 + 1] = a1;
    er[gw * 4 + 2] = a2; er[gw * 4 + 3] = a3;
  }
}

// ------------- CSR build -------------
__global__ void count_kernel(const int* __restrict__ dst, int* __restrict__ cnt, int E) {
  for (int i = blockIdx.x * blockDim.x + threadIdx.x; i < E; i += gridDim.x * blockDim.x)
    atomicAdd(&cnt[dst[i]], 1);
}

__global__ __launch_bounds__(256) void scan_reduce_kernel(
    const int* __restrict__ data, int* __restrict__ bsum, int n) {
  const int base = blockIdx.x * 1024;
  int s = 0;
  for (int i = threadIdx.x; i < 1024; i += 256) {
    const int idx = base + i;
    s += (idx < n) ? data[idx] : 0;
  }
#pragma unroll
  for (int o = 32; o; o >>= 1) s += __shfl_xor(s, o);
  __shared__ int ws[4];
  if ((threadIdx.x & 63) == 0) ws[threadIdx.x >> 6] = s;
  __syncthreads();
  if (threadIdx.x == 0) bsum[blockIdx.x] = ws[0] + ws[1] + ws[2] + ws[3];
}

__global__ __launch_bounds__(1024) void scan_blocksums_kernel(
    int* __restrict__ bsum, int nb) {
  __shared__ int sm[1024];
  const int t = threadIdx.x;
  const int v = (t < nb) ? bsum[t] : 0;
  sm[t] = v;
  __syncthreads();
  for (int ofs = 1; ofs < 1024; ofs <<= 1) {
    const int tmp = (t >= ofs) ? sm[t - ofs] : 0;
    __syncthreads();
    sm[t] += tmp;
    __syncthreads();
  }
  if (t < nb) bsum[t] = sm[t] - v;
}

__global__ __launch_bounds__(1024) void scan_final_kernel(
    int* __restrict__ data, const int* __restrict__ bsum, int n) {
  __shared__ int sm[1024];
  const int t = threadIdx.x;
  const int i = blockIdx.x * 1024 + t;
  const int v = (i < n) ? data[i] : 0;
  sm[t] = v;
  __syncthreads();
  for (int ofs = 1; ofs < 1024; ofs <<= 1) {
    const int tmp = (t >= ofs) ? sm[t - ofs] : 0;
    __syncthreads();
    sm[t] += tmp;
    __syncthreads();
  }
  const int c = bsum[blockIdx.x];
  if (i < n) data[i] = c + sm[t] - v;
  if (i == n - 1) data[n] = c + sm[t];
}

__global__ void fill_kernel(const int* __restrict__ src, const int* __restrict__ dst,
                            const int* __restrict__ off, int* __restrict__ cursor,
                            int* __restrict__ csrsrc, int E) {
  for (int i = blockIdx.x * blockDim.x + threadIdx.x; i < E; i += gridDim.x * blockDim.x) {
    const int d = dst[i];
    const int p = atomicAdd(&cursor[d], 1);
    csrsrc[off[d] + p] = src[i];
  }
}

// ------------- per-relation edge walk (8-edge clamp-padded batches, bf16 gather, exp2) -------------
__device__ __forceinline__ float4 agg_walk(
    const short* __restrict__ Fp, const float* __restrict__ el, float ern,
    const int* __restrict__ csr, int s0, int s1, int myh, int lane) {
  float4 acc = {0.f, 0.f, 0.f, 0.f};
  float ssum = 0.f;
  for (int p = s0; p < s1; p += 8) {
    const int nb = s1 - p;
    int srcs[8];
#pragma unroll
    for (int b = 0; b < 8; ++b) {
      const int q = (b < nb) ? b : nb - 1;
      srcs[b] = csr[p + q];
    }
    float w8[8];
#pragma unroll
    for (int b = 0; b < 8; ++b) {
      float e = el[srcs[b] * 4 + myh] + ern;
      e = e > 0.f ? e : 0.2f * e;
      w8[b] = (b < nb) ? exp2f(e) : 0.f;
    }
    short4v f8[8];
#pragma unroll
    for (int b = 0; b < 8; ++b)
      f8[b] = *reinterpret_cast<const short4v*>(&Fp[(size_t)srcs[b] * 256 + lane * 4]);
#pragma unroll
    for (int b = 0; b < 8; ++b) {
      ssum += w8[b];
      acc.x = fmaf(w8[b], bits2f(f8[b][0]), acc.x);
      acc.y = fmaf(w8[b], bits2f(f8[b][1]), acc.y);
      acc.z = fmaf(w8[b], bits2f(f8[b][2]), acc.z);
      acc.w = fmaf(w8[b], bits2f(f8[b][3]), acc.w);
    }
  }
  const float inv = ssum > 0.f ? 1.f / ssum : 0.f;
  float4 r = {acc.x * inv, acc.y * inv, acc.z * inv, acc.w * inv};
  return r;
}

// ------------- fused GAT aggregate -------------
__global__ __launch_bounds__(256) void gat_agg_fused(
    const bf16* __restrict__ F1, const float* __restrict__ el1,
    const float* __restrict__ er1, const int* __restrict__ off1,
    const int* __restrict__ csr1,
    const bf16* __restrict__ F2, const float* __restrict__ el2,
    const float* __restrict__ er2, const int* __restrict__ off2,
    const int* __restrict__ csr2,
    const float* __restrict__ bias1, const float* __restrict__ bias2,
    float* __restrict__ outF, bf16* __restrict__ outHi, bf16* __restrict__ outLo,
    const float* __restrict__ wr2, float* __restrict__ erOut,
    int n_dst) {
  const int lane = threadIdx.x & 63;
  const int myh = lane >> 4;
  const int gw = (blockIdx.x * blockDim.x + threadIdx.x) >> 6;
  if (gw >= n_dst) return;

  float4 res = agg_walk((const short*)F1, el1, er1[gw * 4 + myh],
                        csr1, off1[gw], off1[gw + 1], myh, lane);
  if (F2) {
    const float4 r2 = agg_walk((const short*)F2, el2, er2[gw * 4 + myh],
                               csr2, off2[gw], off2[gw + 1], myh, lane);
    res.x += r2.x; res.y += r2.y; res.z += r2.z; res.w += r2.w;
  }
  {
    float4 bb = *reinterpret_cast<const float4*>(&bias1[lane * 4]);
    if (bias2) {
      const float4 b2 = *reinterpret_cast<const float4*>(&bias2[lane * 4]);
      bb.x += b2.x; bb.y += b2.y; bb.z += b2.z; bb.w += b2.w;
    }
    res.x = fmaxf(res.x + bb.x, 0.f);
    res.y = fmaxf(res.y + bb.y, 0.f);
    res.z = fmaxf(res.z + bb.z, 0.f);
    res.w = fmaxf(res.w + bb.w, 0.f);
  }
  if (outF) {
    *reinterpret_cast<float4*>(&outF[(size_t)gw * 256 + lane * 4]) = res;
  } else {
    const float rv[4] = {res.x, res.y, res.z, res.w};
    short4v hv, lv;
#pragma unroll
    for (int j = 0; j < 4; ++j) {
      bf16 h = __float2bfloat16(rv[j]);
      float r = rv[j] - __bfloat162float(h);
      bf16 l = __float2bfloat16(r);
      hv[j] = *reinterpret_cast<const short*>(&h);
      lv[j] = *reinterpret_cast<const short*>(&l);
    }
    *reinterpret_cast<short4v*>(&((short*)outHi)[(size_t)gw * 256 + lane * 4]) = hv;
    *reinterpret_cast<short4v*>(&((short*)outLo)[(size_t)gw * 256 + lane * 4]) = lv;
  }
  if (erOut) {
    float4 wv0 = *reinterpret_cast<const float4*>(&wr2[(lane * 4 + 0) * 4]);
    float4 wv1 = *reinterpret_cast<const float4*>(&wr2[(lane * 4 + 1) * 4]);
    float4 wv2 = *reinterpret_cast<const float4*>(&wr2[(lane * 4 + 2) * 4]);
    float4 wv3 = *reinterpret_cast<const float4*>(&wr2[(lane * 4 + 3) * 4]);
    float e0 = res.x * wv0.x + res.y * wv1.x + res.z * wv2.x + res.w * wv3.x;
    float e1 = res.x * wv0.y + res.y * wv1.y + res.z * wv2.y + res.w * wv3.y;
    float e2 = res.x * wv0.z + res.y * wv1.z + res.z * wv2.z + res.w * wv3.z;
    float e3 = res.x * wv0.w + res.y * wv1.w + res.z * wv2.w + res.w * wv3.w;
#pragma unroll
    for (int o = 32; o; o >>= 1) {
      e0 += __shfl_xor(e0, o);
      e1 += __shfl_xor(e1, o);
      e2 += __shfl_xor(e2, o);
      e3 += __shfl_xor(e3, o);
    }
    if (lane == 0) {
      erOut[gw * 4 + 0] = e0; erOut[gw * 4 + 1] = e1;
      erOut[gw * 4 + 2] = e2; erOut[gw * 4 + 3] = e3;
    }
  }
}

// ---------- graph readout stage 1 ----------
__global__ __launch_bounds__(256) void graph_sum_v3(
    const float* __restrict__ h, const int* __restrict__ gid,
    float* __restrict__ pbuf, int n) {
  __shared__ float sm[NGRAPH * 256];
  const int t = threadIdx.x;
  for (int i = t; i < NGRAPH * 256; i += 256) sm[i] = 0.f;
  __syncthreads();
  const int chunk = (n + RD_STRIPES - 1) / RD_STRIPES;
  const int lo = blockIdx.x * chunk;
  const int hiN = min(n, lo + chunk);
#pragma unroll 8
  for (int node = lo; node < hiN; ++node) {
    const int g = gid[node];
    const float v = h[(size_t)node * 256 + t];
    sm[g * 256 + t] += v;
  }
  __syncthreads();
  float* dst = pbuf + (size_t)blockIdx.x * (NGRAPH * 256);
  for (int i = t; i < NGRAPH * 256; i += 256) dst[i] = sm[i];
}

// ---------- graph readout stage 2 ----------
__global__ __launch_bounds__(256) void graph_reduce_kernel(
    const float* __restrict__ pbuf, float* __restrict__ gsum, int colofs) {
  const int g = blockIdx.x, t = threadIdx.x;
  float acc = 0.f;
#pragma unroll 8
  for (int s = 0; s < RD_STRIPES; ++s)
    acc += pbuf[(size_t)s * (NGRAPH * 256) + g * 256 + t];
  gsum[(size_t)g * 512 + colofs + t] = acc;
}

// ---------- graph node-count ----------
__global__ __launch_bounds__(256) void graph_count_kernel(
    const int* __restrict__ gid, int* __restrict__ gcnt, int n, int cntofs) {
  __shared__ int c[NGRAPH];
  if (threadIdx.x < NGRAPH) c[threadIdx.x] = 0;
  __syncthreads();
  for (int i = blockIdx.x * blockDim.x + threadIdx.x; i < n; i += gridDim.x * blockDim.x)
    atomicAdd(&c[gid[i]], 1);
  __syncthreads();
  if (threadIdx.x < NGRAPH && c[threadIdx.x])
    atomicAdd(&gcnt[cntofs + threadIdx.x], c[threadIdx.x]);
}

// ---------- final MLP ----------
__global__ __launch_bounds__(256) void mlp_kernel(
    const float* __restrict__ gsum, const int* __restrict__ gcnt,
    const float* __restrict__ Wm, const float* __restrict__ bm,
    float* __restrict__ out) {
  __shared__ float g[512];
  const int b = blockIdx.x, t = threadIdx.x;
  const float cl = fmaxf((float)gcnt[b], 1.f);
  const float cp = fmaxf((float)gcnt[64 + b], 1.f);
  for (int k = t; k < 512; k += 256)
    g[k] = gsum[(size_t)b * 512 + k] * (k < 256 ? 1.f / cl : 1.f / cp);
  __syncthreads();
  float acc = bm[t];
  for (int k = 0; k < 512; ++k) acc = fmaf(g[k], Wm[(size_t)k * 256 + t], acc);
  out[b * 256 + t] = fmaxf(acc, 0.f);
}

// =====================================================================
extern "C" void kernel_launch(void* const* d_in, const int* in_sizes, int n_in,
                              void* d_out, int out_size, void* d_ws, size_t ws_size,
                              hipStream_t stream) {
  const float* x_lig  = (const float*)d_in[0];
  const float* x_pro  = (const float*)d_in[1];
  const float* W1_ll  = (const float*)d_in[2];
  const float* al1_ll = (const float*)d_in[3];
  const float* ar1_ll = (const float*)d_in[4];
  const float* b1_ll  = (const float*)d_in[5];
  const float* W1_lps = (const float*)d_in[6];
  const float* W1_lpd = (const float*)d_in[7];
  const float* al1_lp = (const float*)d_in[8];
  const float* ar1_lp = (const float*)d_in[9];
  const float* b1_lp  = (const float*)d_in[10];
  const float* W1_pls = (const float*)d_in[11];
  const float* W1_pld = (const float*)d_in[12];
  const float* al1_pl = (const float*)d_in[13];
  const float* ar1_pl = (const float*)d_in[14];
  const float* b1_pl  = (const float*)d_in[15];
  const float* W2_ll  = (const float*)d_in[16];
  const float* al2_ll = (const float*)d_in[17];
  const float* ar2_ll = (const float*)d_in[18];
  const float* b2_ll  = (const float*)d_in[19];
  const float* W2_lps = (const float*)d_in[20];
  const float* W2_lpd = (const float*)d_in[21];
  const float* al2_lp = (const float*)d_in[22];
  const float* ar2_lp = (const float*)d_in[23];
  const float* b2_lp  = (const float*)d_in[24];
  const float* W2_pls = (const float*)d_in[25];
  const float* W2_pld = (const float*)d_in[26];
  const float* al2_pl = (const float*)d_in[27];
  const float* ar2_pl = (const float*)d_in[28];
  const float* b2_pl  = (const float*)d_in[29];
  const float* W_mlp  = (const float*)d_in[30];
  const float* b_mlp  = (const float*)d_in[31];
  const int* src_ll   = (const int*)d_in[32];
  const int* dst_ll   = (const int*)d_in[33];
  const int* src_lp   = (const int*)d_in[34];
  const int* dst_lp   = (const int*)d_in[35];
  const int* src_pl   = (const int*)d_in[36];
  const int* dst_pl   = (const int*)d_in[37];
  const int* gid_lig  = (const int*)d_in[38];
  const int* gid_pro  = (const int*)d_in[39];
  float* out = (float*)d_out;
  (void)in_sizes; (void)n_in; (void)out_size; (void)ws_size;

  // -------- workspace carving (~193 MB) --------
  size_t cur = 0;
  auto carve = [&](size_t bytes) -> char* {
    char* p = (char*)d_ws + cur;
    cur += (bytes + 511) & ~(size_t)511;
    return p;
  };
  const size_t NB   = (size_t)40000 * 256 * sizeof(float);
  const size_t NBH  = (size_t)40000 * 256 * sizeof(bf16);
  bf16* FbA   = (bf16*)carve(NBH);
  bf16* FbB   = (bf16*)carve(NBH);
  bf16* FbC   = (bf16*)carve(NBH);
  char* S1    = carve(NB);
  char* S2P   = carve(NB);
  float* hX   = (float*)carve(NB);
  float* elA  = (float*)carve((size_t)40000 * 4 * sizeof(float));
  float* erA  = (float*)carve((size_t)40000 * 4 * sizeof(float));
  float* elB  = (float*)carve((size_t)40000 * 4 * sizeof(float));
  float* erB  = (float*)carve((size_t)40000 * 4 * sizeof(float));
  float* elC  = (float*)carve((size_t)40000 * 4 * sizeof(float));
  float* erPL = (float*)carve((size_t)40000 * 4 * sizeof(float));
  float* erLP = (float*)carve((size_t)40000 * 4 * sizeof(float));
  float* wr1  = (float*)carve((size_t)256 * 4 * sizeof(float));
  float* wrA  = (float*)carve((size_t)256 * 4 * sizeof(float));
  float* wrB  = (float*)carve((size_t)256 * 4 * sizeof(float));
  bf16* Bthi  = (bf16*)carve((size_t)512 * 256 * sizeof(bf16));
  bf16* Btlo  = (bf16*)carve((size_t)512 * 256 * sizeof(bf16));
  float* gsum = (float*)carve((size_t)64 * 512 * sizeof(float));
  int* gcnt   = (int*)carve(128 * sizeof(int));
  int* bsum   = (int*)carve(1025 * sizeof(int));
  int* off_ll = (int*)carve((NLIG + 1) * sizeof(int));
  int* off_lp = (int*)carve((NPRO + 1) * sizeof(int));
  int* off_pl = (int*)carve((NLIG + 1) * sizeof(int));
  int* cursor = (int*)carve((NLIG + 1) * sizeof(int));
  int* csr_ll = (int*)carve((size_t)ELL * sizeof(int));
  int* csr_lp = (int*)carve((size_t)ELP * sizeof(int));
  int* csr_pl = (int*)carve((size_t)EPL * sizeof(int));

  // overlays / sub-pointers
  bf16* XLhi = (bf16*)S1;
  bf16* XLlo = XLhi + (size_t)40000 * 96;
  bf16* XPhi = (bf16*)S2P;
  bf16* XPlo = XPhi + (size_t)40000 * 128;
  bf16* S1hi = (bf16*)S1;
  bf16* S1lo = S1hi + (size_t)40000 * 256;
  bf16* S2hi = (bf16*)S2P;
  bf16* S2lo = S2hi + (size_t)40000 * 256;
  float* P2  = (float*)S2P;
  float* pbuf = (float*)FbA;

  const int B256 = 256;
  auto thrGrid  = [](long long n) { return (int)((n + 255) / 256); };
  auto waveGrid = [](int n) { return (n + 3) / 4; };

  auto conv_a = [&](const float* A, bf16* hi, bf16* lo, int M, int K, int Kp) {
    convA_kernel<<<(M + 7) / 8, B256, 0, stream>>>(A, hi, lo, M, K, Kp);
  };
  auto run_mfma = [&](const bf16* ahi, const bf16* alo,
                      const float* Wa, const float* Wb, int K, int Kp, int M,
                      bf16* C0, bf16* C1,
                      const float* al0, float* el0, const float* ar0, float* er0,
                      const float* al1, float* el1) {
    convBt_kernel<<<256, B256, 0, stream>>>(Wa, Bthi, Btlo, K, Kp);
    if (Wb)
      convBt_kernel<<<256, B256, 0, stream>>>(Wb, Bthi + (size_t)256 * Kp,
                                              Btlo + (size_t)256 * Kp, K, Kp);
    const int log2ncb = Wb ? 2 : 1;
    const int nrt = (M + 127) / 128;
    const int nb = ((nrt + 7) / 8) * 8 * (1 << log2ncb);
    mfma_gemm<<<nb, B256, 0, stream>>>(ahi, alo, Bthi, Btlo, C0, C1, M, Kp, log2ncb,
                                       al0, el0, ar0, er0, al1, el1);
  };
  auto run_scan = [&](int* data, int n) {
    const int nb = (n + 1023) / 1024;
    scan_reduce_kernel<<<nb, B256, 0, stream>>>(data, bsum, n);
    scan_blocksums_kernel<<<1, 1024, 0, stream>>>(bsum, nb);
    scan_final_kernel<<<nb, 1024, 0, stream>>>(data, bsum, n);
  };

  // -------- CSR builds --------
  struct Rel { const int* src; const int* dst; int* off; int* csr; int E; int Nd; };
  Rel rels[3] = {
    {src_ll, dst_ll, off_ll, csr_ll, ELL, NLIG},
    {src_lp, dst_lp, off_lp, csr_lp, ELP, NPRO},
    {src_pl, dst_pl, off_pl, csr_pl, EPL, NLIG},
  };
  for (int r = 0; r < 3; ++r) {
    hipMemsetAsync(rels[r].off, 0, (rels[r].Nd + 1) * sizeof(int), stream);
    count_kernel<<<thrGrid(rels[r].E), B256, 0, stream>>>(rels[r].dst, rels[r].off, rels[r].E);
    run_scan(rels[r].off, rels[r].Nd);
    hipMemsetAsync(cursor, 0, (rels[r].Nd + 1) * sizeof(int), stream);
    fill_kernel<<<thrGrid(rels[r].E), B256, 0, stream>>>(
        rels[r].src, rels[r].dst, rels[r].off, cursor, rels[r].csr, rels[r].E);
  }

  // ================= LAYER 1 =================
  conv_a(x_lig, XLhi, XLlo, NLIG, 74, 96);
  conv_a(x_pro, XPhi, XPlo, NPRO, 128, 128);
  // merged: FbA = x_lig@W1_ll (+elA,erA), FbC = x_lig@W1_lps (+elC)
  run_mfma(XLhi, XLlo, W1_ll, W1_lps, 74, 96, NLIG,
           FbA, FbC, al1_ll, elA, ar1_ll, erA, al1_lp, elC);
  // pl src GEMM: FbB = x_pro @ W1_pls (+elB)
  run_mfma(XPhi, XPlo, W1_pls, nullptr, 128, 128, NPRO,
           FbB, nullptr, al1_pl, elB, nullptr, nullptr, nullptr, nullptr);
  // pl dst er: erB = x_lig @ (W1_pld . ar1_pl)  [LOG2E-scaled]
  make_wr_kernel<<<(74 * 4 + 255) / 256, B256, 0, stream>>>(W1_pld, ar1_pl, wr1, 74);
  er_gemv_kernel<<<waveGrid(NLIG), B256, 0, stream>>>(x_lig, wr1, erB, NLIG, 74);
  // layer-2 dst weights (scaled)
  make_wr_kernel<<<(256 * 4 + 255) / 256, B256, 0, stream>>>(W2_pld, ar2_pl, wrA, 256);
  make_wr_kernel<<<(256 * 4 + 255) / 256, B256, 0, stream>>>(W2_lpd, ar2_lp, wrB, 256);
  // fused dual agg -> S1 (bf16 split) + erPL
  gat_agg_fused<<<waveGrid(NLIG), B256, 0, stream>>>(
      FbA, elA, erA, off_ll, csr_ll,
      FbB, elB, erB, off_pl, csr_pl,
      b1_ll, b1_pl, nullptr, S1hi, S1lo, wrA, erPL, NLIG);
  // lp dst er: erB = x_pro @ (W1_lpd . ar1_lp)
  make_wr_kernel<<<(128 * 4 + 255) / 256, B256, 0, stream>>>(W1_lpd, ar1_lp, wr1, 128);
  er_gemv_kernel<<<waveGrid(NPRO), B256, 0, stream>>>(x_pro, wr1, erB, NPRO, 128);
  // fused single agg (lp: FbC) -> S2 (bf16 split) + erLP
  gat_agg_fused<<<waveGrid(NPRO), B256, 0, stream>>>(
      FbC, elC, erB, off_lp, csr_lp,
      nullptr, nullptr, nullptr, nullptr, nullptr,
      b1_lp, nullptr, nullptr, S2hi, S2lo, wrB, erLP, NPRO);

  // ================= LAYER 2 =================
  run_mfma(S1hi, S1lo, W2_ll, W2_lps, 256, 256, NLIG,
           FbA, FbC, al2_ll, elA, ar2_ll, erA, al2_lp, elC);
  run_mfma(S2hi, S2lo, W2_pls, nullptr, 256, 256, NPRO,
           FbB, nullptr, al2_pl, elB, nullptr, nullptr, nullptr, nullptr);
  gat_agg_fused<<<waveGrid(NLIG), B256, 0, stream>>>(
      FbA, elA, erA, off_ll, csr_ll,
      FbB, elB, erPL, off_pl, csr_pl,
      b2_ll, b2_pl, hX, nullptr, nullptr, nullptr, nullptr, NLIG);
  gat_agg_fused<<<waveGrid(NPRO), B256, 0, stream>>>(
      FbC, elC, erLP, off_lp, csr_lp,
      nullptr, nullptr, nullptr, nullptr, nullptr,
      b2_lp, nullptr, P2, nullptr, nullptr, nullptr, nullptr, NPRO);

  // ================= READOUT (FbA dead -> pbuf) + MLP =================
  hipMemsetAsync(gcnt, 0, 128 * sizeof(int), stream);
  graph_sum_v3<<<RD_STRIPES, B256, 0, stream>>>(hX, gid_lig, pbuf, NLIG);
  graph_reduce_kernel<<<NGRAPH, B256, 0, stream>>>(pbuf, gsum, 0);
  graph_count_kernel<<<64, B256, 0, stream>>>(gid_lig, gcnt, NLIG, 0);
  graph_sum_v3<<<RD_STRIPES, B256, 0, stream>>>(P2, gid_pro, pbuf, NPRO);
  graph_reduce_kernel<<<NGRAPH, B256, 0, stream>>>(pbuf, gsum, 256);
  graph_count_kernel<<<64, B256, 0, stream>>>(gid_pro, gcnt, NPRO, 64);
  mlp_kernel<<<64, B256, 0, stream>>>(gsum, gcnt, W_mlp, b_mlp, out);
}